// Round 8
// baseline (100.080 us; speedup 1.0000x reference)
//
#include <hip/hip_runtime.h>
#include <math.h>

#define NB   16384
#define SEQ  10
#define DIM  8
#define TRIL 36

__device__ __forceinline__ constexpr int tri(int r, int c) { return r * (r + 1) / 2 + c; } // r >= c

// ---- DPP cross-lane within each 8-lane group (pure VALU, no LDS) ----
// quad_perm ctrls: xor1=0xB1, xor2=0x4E, xor3=0x1B. ROW_HALF_MIRROR=0x141 swaps
// lane i <-> 7-i within each 8-lane half-row (= xor7 for 3-bit lane ids).
template <int CTRL>
__device__ __forceinline__ float fperm(float v) {
    return __int_as_float(__builtin_amdgcn_mov_dpp(__float_as_int(v), CTRL, 0xf, 0xf, true));
}
template <int CTRL>
__device__ __forceinline__ double dperm(double v) {
    long long u = __double_as_longlong(v);
    int lo = (int)(u & 0xffffffffLL);
    int hi = (int)(((unsigned long long)u) >> 32);
    lo = __builtin_amdgcn_mov_dpp(lo, CTRL, 0xf, 0xf, true);
    hi = __builtin_amdgcn_mov_dpp(hi, CTRL, 0xf, 0xf, true);
    return __longlong_as_double(((long long)hi << 32) | (long long)(unsigned)lo);
}

// ---- fp64 rsqrt/rcp: HW seed (>=2^-14) + ONE Newton -> >=2^-28 relative ----
__device__ __forceinline__ double rsqrt1(double x) {
    double r = __builtin_amdgcn_rsq(x);
    return r * (1.5 - 0.5 * x * r * r);
}
__device__ __forceinline__ double rcp1(double x) {
    double r = __builtin_amdgcn_rcp(x);
    return r * (2.0 - x * r);
}
__device__ __forceinline__ double sqrt1(double x) { return x * rsqrt1(x); }

// 144B embedding row = 9 aligned float4
__device__ __forceinline__ void load_row(const float* __restrict__ emb, int tok, float (&F)[TRIL]) {
    const float4* q = (const float4*)(emb + (size_t)tok * TRIL);
    #pragma unroll
    for (int i = 0; i < 9; ++i) {
        float4 v = q[i];
        F[4*i+0] = v.x; F[4*i+1] = v.y; F[4*i+2] = v.z; F[4*i+3] = v.w;
    }
}

// density = (L L^T + 2e-6 I) / (||L||_F^2 + 1.6e-5 + 1e-6), diag(L) clamped >= 1e-4 in fp32.
// fp64 products/sums: density errors perturb eigenvalues ABSOLUTELY (up to ~500x amplified
// through sqrt(lambda+1e-6)), so this stage stays fp64.
template <bool ACCUM>
__device__ __forceinline__ void density_from(float (&Lf)[TRIL], double (&dst)[TRIL]) {
    #pragma unroll
    for (int d = 0; d < DIM; ++d) Lf[tri(d, d)] = fmaxf(Lf[tri(d, d)], 1.0e-4f);
    double t0 = 0.0, t1 = 0.0, t2 = 0.0, t3 = 0.0;
    #pragma unroll
    for (int i = 0; i < 36; i += 4) {
        double v0 = (double)Lf[i],   v1 = (double)Lf[i+1];
        double v2 = (double)Lf[i+2], v3 = (double)Lf[i+3];
        t0 += v0 * v0; t1 += v1 * v1; t2 += v2 * v2; t3 += v3 * v3;
    }
    double tr = ((t0 + t1) + (t2 + t3)) + 1.6e-5;
    double inv = rcp1(tr + 1.0e-6);
    #pragma unroll
    for (int i = 0; i < DIM; ++i) {
        #pragma unroll
        for (int j = 0; j <= i; ++j) {
            double sum = (i == j) ? 2.0e-6 : 0.0;
            #pragma unroll
            for (int k = 0; k <= j; ++k) sum += (double)Lf[tri(i, k)] * (double)Lf[tri(j, k)];
            if (ACCUM) dst[tri(i, j)] += sum * inv;
            else       dst[tri(i, j)]  = sum * inv;
        }
    }
}

// in-place fp64 Cholesky (lower-sym 36), 1-Newton rsqrt per level
__device__ __forceinline__ void chol36(double (&M)[TRIL]) {
    #pragma unroll
    for (int j = 0; j < DIM; ++j) {
        double d = M[tri(j, j)];
        #pragma unroll
        for (int k = 0; k < j; ++k) d -= M[tri(j, k)] * M[tri(j, k)];
        d = fmax(d, 1.0e-30);
        double invd = rsqrt1(d);
        M[tri(j, j)] = d * invd;
        #pragma unroll
        for (int i = j + 1; i < DIM; ++i) {
            double v = M[tri(i, j)];
            #pragma unroll
            for (int k = 0; k < j; ++k) v -= M[tri(i, k)] * M[tri(j, k)];
            M[tri(i, j)] = v * invd;
        }
    }
}

// ============================ KERNEL 1: gather -> G ============================
// 8 lanes per element: lane h owns G column h; stores G[:,h] (8 fp32) to ws.
__global__ void __launch_bounds__(256, 2)
qcbow_phase1(const int* __restrict__ contexts,  // [NB, SEQ]
             const int* __restrict__ targets,   // [NB]
             const float* __restrict__ emb,     // [100000, TRIL]
             float* __restrict__ ws)            // [NB, 64] G matrices
{
    const int tid = blockIdx.x * 256 + threadIdx.x;
    const int b = tid >> 3;
    const int h = threadIdx.x & 7;
    const bool q0 = (h < 4);

    // token assignment: lane h -> ctx s=h; lanes 0,1 also ctx s=8,9; lanes 4-7 sigma
    const int base = b * SEQ;
    int tok1 = contexts[base + h];
    int tok2 = 0;                               // lanes 2,3: dummy row 0 (valid memory)
    if (h < 2)  tok2 = contexts[base + 8 + h];
    if (h >= 4) tok2 = targets[b];

    float F1[TRIL], F2[TRIL];
    load_row(emb, tok1, F1);
    load_row(emb, tok2, F2);

    double A[TRIL];
    #pragma unroll
    for (int i = 0; i < TRIL; ++i) A[i] = 0.0;
    float cntf = 0.0f;

    if (tok1 != 0) { density_from<true>(F1, A); cntf = 1.0f; }
    double T[TRIL];                             // sigma on lanes 4-7; extra-ctx on lanes 0,1
    density_from<false>(F2, T);
    if (h < 2 && tok2 != 0) {
        #pragma unroll
        for (int i = 0; i < TRIL; ++i) A[i] += T[i];
        cntf += 1.0f;
    }

    // allreduce A,cnt over octet: butterfly over xor generators {1,2,7}, all DPP
    #pragma unroll
    for (int i = 0; i < TRIL; ++i) A[i] += dperm<0xB1>(A[i]);
    cntf += fperm<0xB1>(cntf);
    #pragma unroll
    for (int i = 0; i < TRIL; ++i) A[i] += dperm<0x4E>(A[i]);
    cntf += fperm<0x4E>(cntf);
    #pragma unroll
    for (int i = 0; i < TRIL; ++i) A[i] += dperm<0x141>(A[i]);
    cntf += fperm<0x141>(cntf);

    double invc = rcp1((double)cntf);
    #pragma unroll
    for (int i = 0; i < TRIL; ++i) A[i] *= invc;
    #pragma unroll
    for (int d = 0; d < DIM; ++d) A[tri(d, d)] += 1.0e-6;   // rho_ctx + eps I = sqrt_rho^2

    // ONE chol per lane: quad0 chols rho_ctx (A), quad1 chols sigma (T)
    double M[TRIL];
    #pragma unroll
    for (int i = 0; i < TRIL; ++i) M[i] = q0 ? A[i] : T[i];   // A,T die here
    chol36(M);

    // w = Lw[:,h]: mirror pairing (lane h <-> 7-h). quad1 lane m muxes its own
    // column m and SENDS column 7-m so quad0 lane h receives exactly Lw[:,h].
    const bool h1 = (h & 1), h2 = (h & 2);
    double w[DIM];
    #pragma unroll
    for (int k = 0; k < DIM; ++k) {
        #define E(J) ((k >= (J)) ? M[tri((k >= (J)) ? k : (J), (J))] : 0.0)
        double o0 = h1 ? E(5) : E(4);
        double o1 = h1 ? E(7) : E(6);
        double own = h2 ? o1 : o0;              // Lw[:,h]   (valid on quad1)
        double s0 = h1 ? E(2) : E(3);
        double s1 = h1 ? E(0) : E(1);
        double snd = h2 ? s1 : s0;              // Lw[:,7-h] (valid on quad1)
        #undef E
        double sw = dperm<0x141>(snd);          // quad0 lane h receives Lw[:,h]
        w[k] = q0 ? sw : own;
    }

    // Lc broadcast quad0 -> quad1 via mirror (all quad0 lanes hold identical Lc)
    double Lx[TRIL];
    #pragma unroll
    for (int i = 0; i < TRIL; ++i) Lx[i] = dperm<0x141>(M[i]);
    double Lc[TRIL];
    #pragma unroll
    for (int i = 0; i < TRIL; ++i) Lc[i] = q0 ? M[i] : Lx[i];

    // G[:,h] = Lc^T * w ; eig((rho+epsI) sigma) = sing(G)^2
    float col[DIM];
    #pragma unroll
    for (int i = 0; i < DIM; ++i) {
        double s = 0.0;
        #pragma unroll
        for (int k = i; k < DIM; ++k) s += Lc[tri(k, i)] * w[k];
        col[i] = (float)s;
    }

    // store coalesced: element b = 64 floats = 16 float4; lane h -> slots 2h, 2h+1
    float4* wsv = (float4*)ws;
    wsv[(size_t)b * 16 + h * 2 + 0] = make_float4(col[0], col[1], col[2], col[3]);
    wsv[(size_t)b * 16 + h * 2 + 1] = make_float4(col[4], col[5], col[6], col[7]);
}

// ===================== KERNEL 2: one-sided Jacobi + fidelity =====================
// XOR-pairing recv: partner = lane ^ M within the octet, all DPP.
template <int M>
__device__ __forceinline__ float jrecv(float v) {
    if constexpr (M == 1) return fperm<0xB1>(v);
    else if constexpr (M == 2) return fperm<0x4E>(v);
    else if constexpr (M == 3) return fperm<0x1B>(v);
    else if constexpr (M == 7) return fperm<0x141>(v);
    else if constexpr (M == 4) return fperm<0x141>(fperm<0x1B>(v));
    else if constexpr (M == 5) return fperm<0x141>(fperm<0x4E>(v));
    else                       return fperm<0x141>(fperm<0xB1>(v));   // M == 6
}

// One Jacobi round with carried squared norms; tau from the local view gives
// opposite s / same c on partners => symmetric branch-free update.
template <int M>
__device__ __forceinline__ void jround(float (&o)[DIM], float& xo, bool& conv) {
    float r[DIM];
    #pragma unroll
    for (int k = 0; k < DIM; ++k) r[k] = jrecv<M>(o[k]);
    float xr = jrecv<M>(xo);
    float p0 = fmaf(o[1], r[1], o[0] * r[0]);
    float p1 = fmaf(o[3], r[3], o[2] * r[2]);
    float p2 = fmaf(o[5], r[5], o[4] * r[4]);
    float p3 = fmaf(o[7], r[7], o[6] * r[6]);
    float z  = (p0 + p1) + (p2 + p3);
    float z2 = z * z;
    float d  = xr - xo;
    if (z2 > 1.0e-12f * xo * xr && z2 > 1.0e-12f * d * d) conv = false;
    if (z2 > 1.0e-16f * xo * xr) {   // skip pure-noise rotations; guards rcp(0)
        float tau = d * (0.5f * __builtin_amdgcn_rcpf(z));
        float t = __builtin_amdgcn_rcpf(fabsf(tau) + sqrtf(fmaf(tau, tau, 1.0f)));
        t = (tau >= 0.0f) ? t : -t;
        float c = __builtin_amdgcn_rsqf(fmaf(t, t, 1.0f));
        float s = t * c;
        #pragma unroll
        for (int k = 0; k < DIM; ++k) o[k] = fmaf(c, o[k], -s * r[k]);
        float cc = c * c, ss = s * s, cs2 = 2.0f * c * s;
        xo = fmaf(cc, xo, fmaf(ss, xr, -cs2 * z));
    }
}

// 16 lanes per element (both octets duplicate the same 8-column problem) ->
// 4096 waves = 4 waves/SIMD: the ~70-cycle per-round dependent chains finally
// have co-resident waves to hide behind. Tiny fp32 state, no fp64 arrays.
__global__ void __launch_bounds__(256, 4)
qcbow_phase2(const float* __restrict__ ws,     // [NB, 64] G matrices
             float* __restrict__ out)          // [NB]
{
    const int tid = blockIdx.x * 256 + threadIdx.x;
    const int b = tid >> 4;
    const int h = threadIdx.x & 7;              // column index (octet-local)

    const float4* wsv = (const float4*)ws;
    float4 v0 = wsv[(size_t)b * 16 + h * 2 + 0];
    float4 v1 = wsv[(size_t)b * 16 + h * 2 + 1];
    float col[DIM] = {v0.x, v0.y, v0.z, v0.w, v1.x, v1.y, v1.z, v1.w};

    float q0n = fmaf(col[1], col[1], col[0] * col[0]);
    float q1n = fmaf(col[3], col[3], col[2] * col[2]);
    float q2n = fmaf(col[5], col[5], col[4] * col[4]);
    float q3n = fmaf(col[7], col[7], col[6] * col[6]);
    float xo = (q0n + q1n) + (q2n + q3n);       // carried squared norm

    for (int sweep = 0; sweep < 8; ++sweep) {
        bool conv = true;
        jround<1>(col, xo, conv);
        jround<2>(col, xo, conv);
        jround<3>(col, xo, conv);
        jround<4>(col, xo, conv);
        jround<5>(col, xo, conv);
        jround<6>(col, xo, conv);
        jround<7>(col, xo, conv);
        if (sweep >= 2 && __all(conv)) break;   // wave-uniform exit
    }

    // lambda_h = ||col||^2 fresh in fp64 ; f = sum_h sqrt(lambda+1e-6) over octet
    double xn = 0.0;
    #pragma unroll
    for (int k = 0; k < DIM; ++k) xn += (double)col[k] * (double)col[k];
    double fp = sqrt1(xn + 1.0e-6);
    fp += dperm<0xB1>(fp);
    fp += dperm<0x4E>(fp);
    fp += dperm<0x141>(fp);
    if ((threadIdx.x & 15) == 0) {              // one writer per element
        double f = fmin(fp, 1.0);
        f = fmax(f, 1.0e-8);
        out[b] = (float)(-log(f));
    }
}

extern "C" void kernel_launch(void* const* d_in, const int* in_sizes, int n_in,
                              void* d_out, int out_size, void* d_ws, size_t ws_size,
                              hipStream_t stream) {
    const int*   contexts = (const int*)d_in[0];
    const int*   targets  = (const int*)d_in[1];
    const float* emb      = (const float*)d_in[2];
    float*       out      = (float*)d_out;
    float*       ws       = (float*)d_ws;       // 16384*64*4 = 4 MB used

    qcbow_phase1<<<dim3(NB * 8 / 256),  dim3(256), 0, stream>>>(contexts, targets, emb, ws);
    qcbow_phase2<<<dim3(NB * 16 / 256), dim3(256), 0, stream>>>(ws, out);
}

// Round 9
// 86.474 us; speedup vs baseline: 1.1573x; 1.1573x over previous
//
#include <hip/hip_runtime.h>
#include <math.h>

#define NB   16384
#define SEQ  10
#define DIM  8
#define TRIL 36

__device__ __forceinline__ constexpr int tri(int r, int c) { return r * (r + 1) / 2 + c; } // r >= c

// ---- DPP cross-lane within each 8-lane group (pure VALU, no LDS) ----
// quad_perm ctrls: xor1=0xB1, xor2=0x4E, xor3=0x1B. ROW_HALF_MIRROR=0x141 swaps
// lane i <-> 7-i within each 8-lane half-row (= xor7 for 3-bit lane ids).
template <int CTRL>
__device__ __forceinline__ float fperm(float v) {
    return __int_as_float(__builtin_amdgcn_mov_dpp(__float_as_int(v), CTRL, 0xf, 0xf, true));
}
template <int CTRL>
__device__ __forceinline__ double dperm(double v) {
    long long u = __double_as_longlong(v);
    int lo = (int)(u & 0xffffffffLL);
    int hi = (int)(((unsigned long long)u) >> 32);
    lo = __builtin_amdgcn_mov_dpp(lo, CTRL, 0xf, 0xf, true);
    hi = __builtin_amdgcn_mov_dpp(hi, CTRL, 0xf, 0xf, true);
    return __longlong_as_double(((long long)hi << 32) | (long long)(unsigned)lo);
}

// ---- fp64 rsqrt: HW seed (>=2^-14) + ONE Newton -> >=2^-28 relative ----
__device__ __forceinline__ double rsqrt1(double x) {
    double r = __builtin_amdgcn_rsq(x);
    return r * (1.5 - 0.5 * x * r * r);
}
__device__ __forceinline__ double sqrt1(double x) { return x * rsqrt1(x); }

// 144B embedding row = 9 aligned float4
__device__ __forceinline__ void load_row(const float* __restrict__ emb, int tok, float (&F)[TRIL]) {
    const float4* q = (const float4*)(emb + (size_t)tok * TRIL);
    #pragma unroll
    for (int i = 0; i < 9; ++i) {
        float4 v = q[i];
        F[4*i+0] = v.x; F[4*i+1] = v.y; F[4*i+2] = v.z; F[4*i+3] = v.w;
    }
}

// density via TRACE-PRESCALE: rho = (L L^T + 2e-6 I)/T = L' L'^T + (2e-6/T) I with
// L' = L * T^-1/2, T = ||L||_F^2 + 1.7e-5. Trace+rsqrt in fp32: their error is a
// UNIFORM scale on rho -> purely relative lambda shift -> safe. L' = (double)F * sfd
// is an EXACT fp64 product (24+24<53 bits), so the Gram keeps fp64 absolute accuracy
// (absolute density errors are amplified up to 500x through sqrt(lambda+1e-6)).
// cscale carries 1/sqrt(cnt) for context tokens (folds the masked average in).
template <bool ACCUM>
__device__ __forceinline__ void density_from(float (&Lf)[TRIL], double (&dst)[TRIL], float cscale) {
    #pragma unroll
    for (int d = 0; d < DIM; ++d) Lf[tri(d, d)] = fmaxf(Lf[tri(d, d)], 1.0e-4f);
    float t0 = 0.0f, t1 = 0.0f, t2 = 0.0f, t3 = 0.0f;
    #pragma unroll
    for (int i = 0; i < TRIL; i += 4) {
        t0 = fmaf(Lf[i+0], Lf[i+0], t0);
        t1 = fmaf(Lf[i+1], Lf[i+1], t1);
        t2 = fmaf(Lf[i+2], Lf[i+2], t2);
        t3 = fmaf(Lf[i+3], Lf[i+3], t3);
    }
    float T = ((t0 + t1) + (t2 + t3)) + 1.7e-5f;   // +1.6e-5 (2e-6*8 diag) +1e-6 (EPS)
    float sf = __builtin_amdgcn_rsqf(T) * cscale;
    double sfd = (double)sf;
    double L[TRIL];
    #pragma unroll
    for (int i = 0; i < TRIL; ++i) L[i] = (double)Lf[i] * sfd;   // exact
    double dc = 2.0e-6 * (sfd * sfd);
    #pragma unroll
    for (int i = 0; i < DIM; ++i) {
        #pragma unroll
        for (int j = 0; j <= i; ++j) {
            double sum = ACCUM ? dst[tri(i, j)] : 0.0;
            if (i == j) sum += dc;
            #pragma unroll
            for (int k = 0; k <= j; ++k) sum += L[tri(i, k)] * L[tri(j, k)];
            dst[tri(i, j)] = sum;
        }
    }
}

// in-place fp64 Cholesky (lower-sym 36), 1-Newton rsqrt per level (stays fp64:
// chol backward error is absolute wrt ||A||)
__device__ __forceinline__ void chol36(double (&M)[TRIL]) {
    #pragma unroll
    for (int j = 0; j < DIM; ++j) {
        double d = M[tri(j, j)];
        #pragma unroll
        for (int k = 0; k < j; ++k) d -= M[tri(j, k)] * M[tri(j, k)];
        d = fmax(d, 1.0e-30);
        double invd = rsqrt1(d);
        M[tri(j, j)] = d * invd;
        #pragma unroll
        for (int i = j + 1; i < DIM; ++i) {
            double v = M[tri(i, j)];
            #pragma unroll
            for (int k = 0; k < j; ++k) v -= M[tri(i, k)] * M[tri(j, k)];
            M[tri(i, j)] = v * invd;
        }
    }
}

// XOR-pairing recv: partner = lane ^ M, all DPP (xor4..6 = two chained 1-cycle movs).
template <int M>
__device__ __forceinline__ float jrecv(float v) {
    if constexpr (M == 1) return fperm<0xB1>(v);
    else if constexpr (M == 2) return fperm<0x4E>(v);
    else if constexpr (M == 3) return fperm<0x1B>(v);
    else if constexpr (M == 7) return fperm<0x141>(v);
    else if constexpr (M == 4) return fperm<0x141>(fperm<0x1B>(v));
    else if constexpr (M == 5) return fperm<0x141>(fperm<0x4E>(v));
    else                       return fperm<0x141>(fperm<0xB1>(v));   // M == 6
}

// One Jacobi round with carried squared norms; tau from the local view gives
// opposite s / same c on partners => symmetric branch-free update.
template <int M>
__device__ __forceinline__ void jround(float (&o)[DIM], float& xo, bool& conv) {
    float r[DIM];
    #pragma unroll
    for (int k = 0; k < DIM; ++k) r[k] = jrecv<M>(o[k]);
    float xr = jrecv<M>(xo);
    float p0 = fmaf(o[1], r[1], o[0] * r[0]);
    float p1 = fmaf(o[3], r[3], o[2] * r[2]);
    float p2 = fmaf(o[5], r[5], o[4] * r[4]);
    float p3 = fmaf(o[7], r[7], o[6] * r[6]);
    float z  = (p0 + p1) + (p2 + p3);
    float z2 = z * z;
    float d  = xr - xo;
    if (z2 > 1.0e-12f * xo * xr && z2 > 1.0e-12f * d * d) conv = false;
    if (z2 > 1.0e-16f * xo * xr) {   // skip pure-noise rotations; guards rcp(0)
        float tau = d * (0.5f * __builtin_amdgcn_rcpf(z));
        float t = __builtin_amdgcn_rcpf(fabsf(tau) + sqrtf(fmaf(tau, tau, 1.0f)));
        t = (tau >= 0.0f) ? t : -t;
        float c = __builtin_amdgcn_rsqf(fmaf(t, t, 1.0f));
        float s = t * c;
        #pragma unroll
        for (int k = 0; k < DIM; ++k) o[k] = fmaf(c, o[k], -s * r[k]);
        float cc = c * c, ss = s * s, cs2 = 2.0f * c * s;
        xo = fmaf(cc, xo, fmaf(ss, xr, -cs2 * z));
    }
}

// 8 lanes per element: lane h owns G column h. All cross-lane via DPP (zero LDS).
__global__ void __launch_bounds__(256, 2)
qcbow_kernel(const int* __restrict__ contexts,  // [NB, SEQ]
             const int* __restrict__ targets,   // [NB]
             const float* __restrict__ emb,     // [100000, TRIL]
             float* __restrict__ out)           // [NB]
{
    const int tid = blockIdx.x * 256 + threadIdx.x;
    const int b = tid >> 3;
    const int h = threadIdx.x & 7;
    const bool q0 = (h < 4);

    // ---- token assignment: lane h -> ctx s=h; lanes 0,1 also ctx s=8,9; lanes 4-7 sigma
    const int base = b * SEQ;
    int tok1 = contexts[base + h];
    int tok2 = 0;                               // lanes 2,3: dummy row 0 (valid memory)
    if (h < 2)  tok2 = contexts[base + 8 + h];
    if (h >= 4) tok2 = targets[b];

    // ---- cnt BEFORE densities (ballot+popcount on my octet's 8 bits) so 1/sqrt(cnt)
    // folds into the density prescale -> the fp64 invc pass is eliminated.
    unsigned long long bal1 = __ballot(tok1 != 0);
    unsigned long long bal2 = __ballot(h < 2 && tok2 != 0);
    const int oshift = (threadIdx.x & 63) & 56;
    int cnt = __popcll((bal1 >> oshift) & 0xFFull) + __popcll((bal2 >> oshift) & 0xFFull);
    float rsc = __builtin_amdgcn_rsqf((float)cnt);   // relative-only error: safe

    float F1[TRIL], F2[TRIL];                   // both rows loaded up-front (latency overlap)
    load_row(emb, tok1, F1);
    load_row(emb, tok2, F2);

    double A[TRIL];
    #pragma unroll
    for (int i = 0; i < TRIL; ++i) A[i] = 0.0;

    if (tok1 != 0) density_from<true>(F1, A, rsc);
    double T[TRIL];                             // sigma on lanes 4-7; extra-ctx on lanes 0,1
    density_from<false>(F2, T, (h < 2) ? rsc : 1.0f);
    if (h < 2 && tok2 != 0) {
        #pragma unroll
        for (int i = 0; i < TRIL; ++i) A[i] += T[i];
    }

    // ---- allreduce A over octet: butterfly over xor generators {1,2,7}, all DPP ----
    #pragma unroll
    for (int i = 0; i < TRIL; ++i) A[i] += dperm<0xB1>(A[i]);
    #pragma unroll
    for (int i = 0; i < TRIL; ++i) A[i] += dperm<0x4E>(A[i]);
    #pragma unroll
    for (int i = 0; i < TRIL; ++i) A[i] += dperm<0x141>(A[i]);

    // A is already rho_ctx (cnt folded in); add matrix-sqrt eps
    #pragma unroll
    for (int d = 0; d < DIM; ++d) A[tri(d, d)] += 1.0e-6;   // rho_ctx + eps I = sqrt_rho^2

    // ---- ONE chol per lane: quad0 chols rho_ctx (A), quad1 chols sigma (T) ----
    double M[TRIL];
    #pragma unroll
    for (int i = 0; i < TRIL; ++i) M[i] = q0 ? A[i] : T[i];   // A,T die here
    chol36(M);

    // ---- fp32 from here to G: dG absolute noise e perturbs lambda by <= 2*sqrt(lambda)*e,
    // and the 1/(2 sqrt(lambda+eps)) output amplification cancels the sqrt(lambda):
    // df <= ~5e-7. Halves exchange movs and G FMA issue.
    float Mf[TRIL];
    #pragma unroll
    for (int i = 0; i < TRIL; ++i) Mf[i] = (float)M[i];

    // w = Lw[:,h]: mirror pairing (lane h <-> 7-h). quad1 lane m muxes its own
    // column m and SENDS column 7-m so quad0 lane h receives exactly Lw[:,h].
    const bool h1 = (h & 1), h2 = (h & 2);
    float w[DIM];
    #pragma unroll
    for (int k = 0; k < DIM; ++k) {
        #define E(J) ((k >= (J)) ? Mf[tri((k >= (J)) ? k : (J), (J))] : 0.0f)
        float o0 = h1 ? E(5) : E(4);
        float o1 = h1 ? E(7) : E(6);
        float own = h2 ? o1 : o0;               // Lw[:,h]   (valid on quad1)
        float s0 = h1 ? E(2) : E(3);
        float s1 = h1 ? E(0) : E(1);
        float snd = h2 ? s1 : s0;               // Lw[:,7-h] (valid on quad1)
        #undef E
        float sw = fperm<0x141>(snd);           // quad0 lane h receives Lw[:,h]
        w[k] = q0 ? sw : own;
    }

    // Lc broadcast quad0 -> quad1 via mirror (all quad0 lanes hold identical Lc)
    float Lxf[TRIL];
    #pragma unroll
    for (int i = 0; i < TRIL; ++i) Lxf[i] = fperm<0x141>(Mf[i]);
    float Lcf[TRIL];
    #pragma unroll
    for (int i = 0; i < TRIL; ++i) Lcf[i] = q0 ? Mf[i] : Lxf[i];

    // G[:,h] = Lc^T * w ; eig((rho+epsI) sigma) = sing(G)^2 = final col norms^2
    float col[DIM];
    #pragma unroll
    for (int i = 0; i < DIM; ++i) {
        float s = 0.0f;
        #pragma unroll
        for (int k = i; k < DIM; ++k) s = fmaf(Lcf[tri(k, i)], w[k], s);  // w[k]=0 for k<h
        col[i] = s;
    }

    // ---- 8-processor one-sided Jacobi, XOR pairing: 7 rounds/sweep = all 28 pairs ----
    float q0n = fmaf(col[1], col[1], col[0] * col[0]);
    float q1n = fmaf(col[3], col[3], col[2] * col[2]);
    float q2n = fmaf(col[5], col[5], col[4] * col[4]);
    float q3n = fmaf(col[7], col[7], col[6] * col[6]);
    float xo = (q0n + q1n) + (q2n + q3n);       // carried squared norm
    for (int sweep = 0; sweep < 8; ++sweep) {
        bool conv = true;
        jround<1>(col, xo, conv);
        jround<2>(col, xo, conv);
        jround<3>(col, xo, conv);
        jround<4>(col, xo, conv);
        jround<5>(col, xo, conv);
        jround<6>(col, xo, conv);
        jround<7>(col, xo, conv);
        if (sweep >= 2 && __all(conv)) break;   // wave-uniform exit
    }

    // ---- lambda_h = ||col||^2 fresh in fp64 ; f = sum_h sqrt(lambda+1e-6) over octet ----
    double xn = 0.0;
    #pragma unroll
    for (int k = 0; k < DIM; ++k) xn += (double)col[k] * (double)col[k];
    double fp = sqrt1(xn + 1.0e-6);
    fp += dperm<0xB1>(fp);
    fp += dperm<0x4E>(fp);
    fp += dperm<0x141>(fp);
    if (h == 0) {
        float ff = (float)fmin(fp, 1.0);
        ff = fmaxf(ff, 1.0e-8f);
        out[b] = -logf(ff);                     // fp32 log: ~2e-7 rel, safe
    }
}

extern "C" void kernel_launch(void* const* d_in, const int* in_sizes, int n_in,
                              void* d_out, int out_size, void* d_ws, size_t ws_size,
                              hipStream_t stream) {
    const int*   contexts = (const int*)d_in[0];
    const int*   targets  = (const int*)d_in[1];
    const float* emb      = (const float*)d_in[2];
    float*       out      = (float*)d_out;

    qcbow_kernel<<<dim3(NB * 8 / 256), dim3(256), 0, stream>>>(contexts, targets, emb, out);
}